// Round 1
// 555.782 us; speedup vs baseline: 1.0830x; 1.0830x over previous
//
#include <hip/hip_runtime.h>

#define F_IN 128
#define F_OUT 64
#define NCHUNK 256   // scan chunks per relation

__device__ __forceinline__ unsigned short f2bf(float f) {
    unsigned int u = __float_as_uint(f);
    u += 0x7fff + ((u >> 16) & 1);          // round-nearest-even
    return (unsigned short)(u >> 16);
}
__device__ __forceinline__ float bf2f(unsigned short s) {
    return __uint_as_float((unsigned int)s << 16);
}

// ---------------- degree (dst occurrences; +1 self-loop added later) --------
__global__ __launch_bounds__(256) void deg_kernel(const int* __restrict__ ei,
                                                  int* __restrict__ deg,
                                                  int N, int E) {
    int r = blockIdx.y;
    int e = blockIdx.x * 256 + threadIdx.x;
    if (e >= E) return;
    int d = ei[(size_t)r * 2 * E + E + e];
    atomicAdd(&deg[(size_t)r * N + d], 1);
}

// ---------------- invperm: ip[perm[i]] = i ----------------------------------
__global__ __launch_bounds__(256) void invperm_kernel(const int* __restrict__ perm,
                                                      int* __restrict__ ip, int N) {
    int r = blockIdx.y;
    int i = blockIdx.x * 256 + threadIdx.x;
    if (i >= N) return;
    ip[(size_t)r * N + perm[(size_t)r * N + i]] = i;
}

// ---------------- hierarchical scan, phase 1: per-chunk sums ----------------
__global__ __launch_bounds__(256) void scan_partial(const int* __restrict__ deg,
                                                    int* __restrict__ psum,
                                                    int N, int chunk) {
    int r = blockIdx.y, b = blockIdx.x;
    int start = b * chunk, end = min(start + chunk, N);
    int s = 0;
    for (int i = start + threadIdx.x; i < end; i += 256)
        s += deg[(size_t)r * N + i];
    __shared__ int ls[256];
    ls[threadIdx.x] = s;
    __syncthreads();
    for (int off = 128; off > 0; off >>= 1) {
        if (threadIdx.x < off) ls[threadIdx.x] += ls[threadIdx.x + off];
        __syncthreads();
    }
    if (threadIdx.x == 0) psum[r * NCHUNK + b] = ls[0];
}

// ---------------- phase 2: exclusive scan of chunk sums (1 block) -----------
__global__ __launch_bounds__(256) void scan_offsets(int* __restrict__ psum,
                                                    int* __restrict__ rowstart,
                                                    int N, int R) {
    int tid = threadIdx.x, lane = tid & 63, wv = tid >> 6;
    __shared__ int wsum[4];
    for (int r = 0; r < R; ++r) {
        int v = psum[r * NCHUNK + tid];
        int sc = v;
        #pragma unroll
        for (int off = 1; off < 64; off <<= 1) {
            int t = __shfl_up(sc, off, 64);
            if (lane >= off) sc += t;
        }
        if (lane == 63) wsum[wv] = sc;
        __syncthreads();
        int woff = 0;
        for (int w = 0; w < wv; ++w) woff += wsum[w];
        psum[r * NCHUNK + tid] = woff + sc - v;   // exclusive
        if (tid == 255) rowstart[(size_t)r * (N + 1) + N] = woff + sc;  // total
        __syncthreads();
    }
}

// ---------------- phase 3: re-scan chunk, write rowstart/cursor/dinv --------
__global__ __launch_bounds__(256) void scan_apply(int* __restrict__ deg,
                                                  const int* __restrict__ psum,
                                                  int* __restrict__ rowstart,
                                                  float* __restrict__ dinv,
                                                  int N, int chunk) {
    int r = blockIdx.y, b = blockIdx.x;
    int tid = threadIdx.x, lane = tid & 63, wv = tid >> 6;
    int start = b * chunk, end = min(start + chunk, N);
    int* dg = deg + (size_t)r * N;
    int* rs = rowstart + (size_t)r * (N + 1);
    float* dv = dinv + (size_t)r * N;
    __shared__ int wsum[4];
    int v[4]; int tsum = 0;
    #pragma unroll
    for (int j = 0; j < 4; ++j) {
        int idx = start + tid * 4 + j;
        v[j] = (idx < end) ? dg[idx] : 0;
        tsum += v[j];
    }
    int sc = tsum;
    #pragma unroll
    for (int off = 1; off < 64; off <<= 1) {
        int t = __shfl_up(sc, off, 64);
        if (lane >= off) sc += t;
    }
    if (lane == 63) wsum[wv] = sc;
    __syncthreads();
    int woff = 0;
    for (int w = 0; w < wv; ++w) woff += wsum[w];
    int excl = psum[r * NCHUNK + b] + woff + sc - tsum;
    #pragma unroll
    for (int j = 0; j < 4; ++j) {
        int idx = start + tid * 4 + j;
        if (idx < end) {
            rs[idx] = excl;
            dg[idx] = excl;                       // cursor for fill_csr
            dv[idx] = rsqrtf((float)(v[j] + 1));  // +1 self-loop
        }
        excl += v[j];
    }
}

// ---------------- fill CSR: bucket by dst; store (src, norm) ----------------
__global__ __launch_bounds__(256) void fill_csr(const int* __restrict__ ei,
                                                const float* __restrict__ dinv,
                                                int* __restrict__ cursor,
                                                int2* __restrict__ csr,
                                                int N, int E) {
    int r = blockIdx.y;
    int e = blockIdx.x * 256 + threadIdx.x;
    if (e >= E) return;
    const int* base = ei + (size_t)r * 2 * E;
    int s = base[e], d = base[E + e];
    const float* dv = dinv + (size_t)r * N;
    float nrm = dv[s] * dv[d];
    int pos = atomicAdd(&cursor[(size_t)r * N + d], 1);
    int2 sp; sp.x = s; sp.y = __float_as_int(nrm);
    csr[(size_t)r * E + pos] = sp;
}

// ---------------- XW = x @ W_r -> bf16 combined[i] = (xw[i] | xw[perm[i]]) --
// 64x64 tile/block, 4x4 microtile/thread. Row i's result written to
// combined[i][0:64] (pos) and combined[invperm[i]][64:128] (neg half).
__global__ __launch_bounds__(256) void gemm_xw(const float* __restrict__ x,
                                               const float* __restrict__ W,
                                               const int* __restrict__ ip,
                                               unsigned short* __restrict__ combined,
                                               int N) {
    __shared__ float xs[64 * 68];    // [kk][row], stride 68
    __shared__ float wsd[128 * 68];  // [k][col],  stride 68
    int r = blockIdx.y;
    const float* Wr = W + (size_t)r * F_IN * F_OUT;
    {   // stage W once: thread t -> k = t>>1, cq = t&1, 8 float4 each
        int k = threadIdx.x >> 1, cq = threadIdx.x & 1;
        const float* wrow = Wr + k * F_OUT;
        #pragma unroll
        for (int j = 0; j < 8; ++j) {
            int col = (cq + 2 * j) * 4;
            *(float4*)&wsd[k * 68 + col] = *(const float4*)(wrow + col);
        }
    }
    int row0 = blockIdx.x * 64;
    int ty = threadIdx.x >> 4, tx = threadIdx.x & 15;
    int lrow = threadIdx.x >> 2;
    int kq = threadIdx.x & 3;
    int grow = row0 + lrow; if (grow >= N) grow = N - 1;   // clamp, garbage ok
    const float* xrow = x + (size_t)grow * F_IN;
    float acc[4][4] = {};
    for (int kc = 0; kc < 2; ++kc) {
        __syncthreads();
        #pragma unroll
        for (int j = 0; j < 4; ++j) {
            int kk4 = kq + 4 * j;
            float4 v = *(const float4*)(xrow + kc * 64 + kk4 * 4);
            xs[(kk4 * 4 + 0) * 68 + lrow] = v.x;
            xs[(kk4 * 4 + 1) * 68 + lrow] = v.y;
            xs[(kk4 * 4 + 2) * 68 + lrow] = v.z;
            xs[(kk4 * 4 + 3) * 68 + lrow] = v.w;
        }
        __syncthreads();
        const float* wk = &wsd[kc * 64 * 68];
        #pragma unroll 8
        for (int kk = 0; kk < 64; ++kk) {
            float4 xa = *(const float4*)&xs[kk * 68 + ty * 4];
            float4 wb = *(const float4*)&wk[kk * 68 + tx * 4];
            acc[0][0] += xa.x * wb.x; acc[0][1] += xa.x * wb.y;
            acc[0][2] += xa.x * wb.z; acc[0][3] += xa.x * wb.w;
            acc[1][0] += xa.y * wb.x; acc[1][1] += xa.y * wb.y;
            acc[1][2] += xa.y * wb.z; acc[1][3] += xa.y * wb.w;
            acc[2][0] += xa.z * wb.x; acc[2][1] += xa.z * wb.y;
            acc[2][2] += xa.z * wb.z; acc[2][3] += xa.z * wb.w;
            acc[3][0] += xa.w * wb.x; acc[3][1] += xa.w * wb.y;
            acc[3][2] += xa.w * wb.z; acc[3][3] += xa.w * wb.w;
        }
    }
    const int* ipr = ip + (size_t)r * N;
    #pragma unroll
    for (int i = 0; i < 4; ++i) {
        int orow = row0 + ty * 4 + i;
        if (orow < N) {
            ushort4 v;
            v.x = f2bf(acc[i][0]); v.y = f2bf(acc[i][1]);
            v.z = f2bf(acc[i][2]); v.w = f2bf(acc[i][3]);
            size_t rb = (size_t)r * N;
            // pos half: own row (coalesced)
            *(ushort4*)(combined + (rb + orow) * 128 + tx * 4) = v;
            // neg half of row ip[orow]: wave writes 4 x 128B full segments
            int j = ipr[orow];
            *(ushort4*)(combined + (rb + j) * 128 + 64 + tx * 4) = v;
        }
    }
}

// ---------------- gather: one wave per (r, dst row); fused epilogue ---------
// Lane layout: lane owns combined channels [2*lane, 2*lane+1] (one uint load
// covers the full 256B row per wave). Lanes 0..31 -> pos ch 2l,2l+1;
// lanes 32..63 -> neg ch 2(l-32),2(l-32)+1.
// Edge loop: batch-8 predicated. j0/j1 readfirstlane'd -> csr entries come in
// via scalar loads; all 8 row loads issue before any FMA (1 csr->row round
// trip for deg<=8 instead of ~3-4 dependent ones).
__global__ __launch_bounds__(256) void gather_kernel(const int2* __restrict__ csr,
                                                     const int* __restrict__ rowstart,
                                                     const float* __restrict__ dinv,
                                                     const unsigned short* __restrict__ combined,
                                                     const float* __restrict__ bs,
                                                     float* __restrict__ out_pos,
                                                     float* __restrict__ out_neg,
                                                     float* __restrict__ partial,
                                                     int N, int E) {
    int r = blockIdx.y;
    int lane = threadIdx.x & 63, wv = threadIdx.x >> 6;
    int i = blockIdx.x * 4 + wv;
    i = __builtin_amdgcn_readfirstlane(i);      // wave-uniform, make it scalar
    int c0 = (lane & 31) * 2;                   // output channel pair base
    __shared__ float ls[4][64];
    float p0 = 0.f, p1 = 0.f;                   // pos values for summary
    if (i < N) {
        const unsigned short* cw = combined + (size_t)r * N * 128;
        const int* rs = rowstart + (size_t)r * (N + 1);
        int j0 = rs[i], j1 = rs[i + 1];
        j0 = __builtin_amdgcn_readfirstlane(j0);
        j1 = __builtin_amdgcn_readfirstlane(j1);
        float di = dinv[(size_t)r * N + i];
        float w = di * di;
        // self term: whole 256B row in one coalesced wave access
        unsigned int sv = *(const unsigned int*)(cw + (size_t)i * 128 + 2 * lane);
        float acc0 = bf2f((unsigned short)sv) * w;
        float acc1 = bf2f((unsigned short)(sv >> 16)) * w;
        const int2* cs = csr + (size_t)r * E;
        int last = j1 - 1;
        for (int j = j0; j < j1; j += 8) {
            int2 e[8];
            float nm[8];
            #pragma unroll
            for (int k = 0; k < 8; ++k) {
                int idx = j + k;
                int ic = idx < last ? idx : last;        // clamp: always valid
                e[k] = cs[ic];                            // scalar load (uniform)
                nm[k] = (idx < j1) ? __int_as_float(e[k].y) : 0.f;
            }
            #pragma unroll
            for (int k = 0; k < 8; ++k) {
                unsigned int v = *(const unsigned int*)(cw + (size_t)e[k].x * 128 + 2 * lane);
                acc0 += bf2f((unsigned short)v) * nm[k];
                acc1 += bf2f((unsigned short)(v >> 16)) * nm[k];
            }
        }
        float2 bv = *(const float2*)(bs + r * F_OUT + c0);
        float q0 = acc0 + bv.x; q0 = q0 > 0.f ? q0 : 0.f;
        float q1 = acc1 + bv.y; q1 = q1 > 0.f ? q1 : 0.f;
        size_t off = (size_t)r * N * F_OUT + (size_t)i * F_OUT + c0;
        float* dst = (lane < 32) ? (out_pos + off) : (out_neg + off);
        float2 o; o.x = q0; o.y = q1;
        *(float2*)dst = o;
        if (lane < 32) { p0 = q0; p1 = q1; }
    }
    if (lane < 32) { ls[wv][c0] = p0; ls[wv][c0 + 1] = p1; }
    __syncthreads();
    if (wv == 0) {
        float t = ls[0][lane] + ls[1][lane] + ls[2][lane] + ls[3][lane];
        atomicAdd(&partial[((size_t)r * 256 + (blockIdx.x & 255)) * F_OUT + lane], t);
    }
}

// ---------------- summary = mean over pos rows ------------------------------
__global__ __launch_bounds__(256) void summary_reduce(const float* __restrict__ partial,
                                                      float* __restrict__ summary,
                                                      float inv_n) {
    int r = blockIdx.x;
    int lane = threadIdx.x & 63, wv = threadIdx.x >> 6;
    __shared__ float ls[256];
    float s = 0.f;
    for (int c = wv; c < 256; c += 4)
        s += partial[((size_t)r * 256 + c) * F_OUT + lane];
    ls[threadIdx.x] = s;
    __syncthreads();
    if (wv == 0)
        summary[r * F_OUT + lane] =
            (ls[lane] + ls[64 + lane] + ls[128 + lane] + ls[192 + lane]) * inv_n;
}

extern "C" void kernel_launch(void* const* d_in, const int* in_sizes, int n_in,
                              void* d_out, int out_size, void* d_ws, size_t ws_size,
                              hipStream_t stream) {
    const float* x    = (const float*)d_in[0];
    const int*   ei   = (const int*)d_in[1];
    const int*   perm = (const int*)d_in[2];
    const float* Ws   = (const float*)d_in[3];
    const float* bs   = (const float*)d_in[4];

    const int N = in_sizes[0] / F_IN;          // 100000
    const int R = in_sizes[4] / F_OUT;         // 3
    const int E = in_sizes[1] / (2 * R);       // 600000

    float* out_pos = (float*)d_out;
    float* out_neg = out_pos + (size_t)R * N * F_OUT;
    float* summary = out_neg + (size_t)R * N * F_OUT;

    char* ws = (char*)d_ws;
    size_t off = 0;
    auto alloc = [&](size_t bytes) { void* p = ws + off;
        off += (bytes + 255) & ~(size_t)255; return p; };
    int*   deg      = (int*)  alloc((size_t)R * N * 4);   // -> cursor after scan
    float* dinv     = (float*)alloc((size_t)R * N * 4);
    int*   rowstart = (int*)  alloc((size_t)R * (N + 1) * 4);
    int*   ip       = (int*)  alloc((size_t)R * N * 4);
    int2*  csr      = (int2*) alloc((size_t)R * E * 8);
    unsigned short* combined = (unsigned short*)alloc((size_t)R * N * 128 * 2);
    float* partial  = (float*)alloc((size_t)R * 256 * F_OUT * 4);
    int*   psum     = (int*)  alloc((size_t)R * NCHUNK * 4);

    const int chunk = (N + NCHUNK - 1) / NCHUNK;

    hipMemsetAsync(deg, 0, (size_t)R * N * sizeof(int), stream);
    hipMemsetAsync(partial, 0, (size_t)R * 256 * F_OUT * sizeof(float), stream);

    deg_kernel<<<dim3((E + 255) / 256, R), 256, 0, stream>>>(ei, deg, N, E);
    invperm_kernel<<<dim3((N + 255) / 256, R), 256, 0, stream>>>(perm, ip, N);
    scan_partial<<<dim3(NCHUNK, R), 256, 0, stream>>>(deg, psum, N, chunk);
    scan_offsets<<<1, 256, 0, stream>>>(psum, rowstart, N, R);
    scan_apply<<<dim3(NCHUNK, R), 256, 0, stream>>>(deg, psum, rowstart, dinv, N, chunk);
    fill_csr<<<dim3((E + 255) / 256, R), 256, 0, stream>>>(ei, dinv, deg, csr, N, E);
    gemm_xw<<<dim3((N + 63) / 64, R), 256, 0, stream>>>(x, Ws, ip, combined, N);
    gather_kernel<<<dim3((N + 3) / 4, R), 256, 0, stream>>>(csr, rowstart, dinv,
                                                            combined, bs, out_pos,
                                                            out_neg, partial, N, E);
    summary_reduce<<<R, 256, 0, stream>>>(partial, summary, 1.0f / (float)N);
}

// Round 2
// 543.083 us; speedup vs baseline: 1.1083x; 1.0234x over previous
//
#include <hip/hip_runtime.h>

#define F_IN 128
#define F_OUT 64
#define NCHUNK 256   // scan chunks per relation

typedef float f32x2 __attribute__((ext_vector_type(2)));

__device__ __forceinline__ unsigned short f2bf(float f) {
    unsigned int u = __float_as_uint(f);
    u += 0x7fff + ((u >> 16) & 1);          // round-nearest-even
    return (unsigned short)(u >> 16);
}
__device__ __forceinline__ float bf2f(unsigned short s) {
    return __uint_as_float((unsigned int)s << 16);
}

// ---------------- degree (dst occurrences; +1 self-loop added later) --------
__global__ __launch_bounds__(256) void deg_kernel(const int* __restrict__ ei,
                                                  int* __restrict__ deg,
                                                  int N, int E) {
    int r = blockIdx.y;
    int e = blockIdx.x * 256 + threadIdx.x;
    if (e >= E) return;
    int d = ei[(size_t)r * 2 * E + E + e];
    atomicAdd(&deg[(size_t)r * N + d], 1);
}

// ---------------- invperm: ip[perm[i]] = i ----------------------------------
__global__ __launch_bounds__(256) void invperm_kernel(const int* __restrict__ perm,
                                                      int* __restrict__ ip, int N) {
    int r = blockIdx.y;
    int i = blockIdx.x * 256 + threadIdx.x;
    if (i >= N) return;
    ip[(size_t)r * N + perm[(size_t)r * N + i]] = i;
}

// ---------------- hierarchical scan, phase 1: per-chunk sums ----------------
__global__ __launch_bounds__(256) void scan_partial(const int* __restrict__ deg,
                                                    int* __restrict__ psum,
                                                    int N, int chunk) {
    int r = blockIdx.y, b = blockIdx.x;
    int start = b * chunk, end = min(start + chunk, N);
    int s = 0;
    for (int i = start + threadIdx.x; i < end; i += 256)
        s += deg[(size_t)r * N + i];
    __shared__ int ls[256];
    ls[threadIdx.x] = s;
    __syncthreads();
    for (int off = 128; off > 0; off >>= 1) {
        if (threadIdx.x < off) ls[threadIdx.x] += ls[threadIdx.x + off];
        __syncthreads();
    }
    if (threadIdx.x == 0) psum[r * NCHUNK + b] = ls[0];
}

// ---------------- phase 2: exclusive scan of chunk sums (1 block) -----------
__global__ __launch_bounds__(256) void scan_offsets(int* __restrict__ psum,
                                                    int* __restrict__ rowstart,
                                                    int N, int R) {
    int tid = threadIdx.x, lane = tid & 63, wv = tid >> 6;
    __shared__ int wsum[4];
    for (int r = 0; r < R; ++r) {
        int v = psum[r * NCHUNK + tid];
        int sc = v;
        #pragma unroll
        for (int off = 1; off < 64; off <<= 1) {
            int t = __shfl_up(sc, off, 64);
            if (lane >= off) sc += t;
        }
        if (lane == 63) wsum[wv] = sc;
        __syncthreads();
        int woff = 0;
        for (int w = 0; w < wv; ++w) woff += wsum[w];
        psum[r * NCHUNK + tid] = woff + sc - v;   // exclusive
        if (tid == 255) rowstart[(size_t)r * (N + 1) + N] = woff + sc;  // total
        __syncthreads();
    }
}

// ---------------- phase 3: re-scan chunk, write rowstart/cursor/dinv --------
__global__ __launch_bounds__(256) void scan_apply(int* __restrict__ deg,
                                                  const int* __restrict__ psum,
                                                  int* __restrict__ rowstart,
                                                  float* __restrict__ dinv,
                                                  int N, int chunk) {
    int r = blockIdx.y, b = blockIdx.x;
    int tid = threadIdx.x, lane = tid & 63, wv = tid >> 6;
    int start = b * chunk, end = min(start + chunk, N);
    int* dg = deg + (size_t)r * N;
    int* rs = rowstart + (size_t)r * (N + 1);
    float* dv = dinv + (size_t)r * N;
    __shared__ int wsum[4];
    int v[4]; int tsum = 0;
    #pragma unroll
    for (int j = 0; j < 4; ++j) {
        int idx = start + tid * 4 + j;
        v[j] = (idx < end) ? dg[idx] : 0;
        tsum += v[j];
    }
    int sc = tsum;
    #pragma unroll
    for (int off = 1; off < 64; off <<= 1) {
        int t = __shfl_up(sc, off, 64);
        if (lane >= off) sc += t;
    }
    if (lane == 63) wsum[wv] = sc;
    __syncthreads();
    int woff = 0;
    for (int w = 0; w < wv; ++w) woff += wsum[w];
    int excl = psum[r * NCHUNK + b] + woff + sc - tsum;
    #pragma unroll
    for (int j = 0; j < 4; ++j) {
        int idx = start + tid * 4 + j;
        if (idx < end) {
            rs[idx] = excl;
            dg[idx] = excl;                       // cursor for fill_csr
            dv[idx] = rsqrtf((float)(v[j] + 1));  // +1 self-loop
        }
        excl += v[j];
    }
}

// ---------------- fill CSR: bucket by dst; store (src, norm) ----------------
__global__ __launch_bounds__(256) void fill_csr(const int* __restrict__ ei,
                                                const float* __restrict__ dinv,
                                                int* __restrict__ cursor,
                                                int2* __restrict__ csr,
                                                int N, int E) {
    int r = blockIdx.y;
    int e = blockIdx.x * 256 + threadIdx.x;
    if (e >= E) return;
    const int* base = ei + (size_t)r * 2 * E;
    int s = base[e], d = base[E + e];
    const float* dv = dinv + (size_t)r * N;
    float nrm = dv[s] * dv[d];
    int pos = atomicAdd(&cursor[(size_t)r * N + d], 1);
    int2 sp; sp.x = s; sp.y = __float_as_int(nrm);
    csr[(size_t)r * E + pos] = sp;
}

// ---------------- XW = x @ W_r -> bf16 combined[i] = (xw[i] | xw[perm[i]]) --
// 64x64 tile/block, 4x4 microtile/thread. Row i's result written to
// combined[i][0:64] (pos) and combined[invperm[i]][64:128] (neg half).
__global__ __launch_bounds__(256) void gemm_xw(const float* __restrict__ x,
                                               const float* __restrict__ W,
                                               const int* __restrict__ ip,
                                               unsigned short* __restrict__ combined,
                                               int N) {
    __shared__ float xs[64 * 68];    // [kk][row], stride 68
    __shared__ float wsd[128 * 68];  // [k][col],  stride 68
    int r = blockIdx.y;
    const float* Wr = W + (size_t)r * F_IN * F_OUT;
    {   // stage W once: thread t -> k = t>>1, cq = t&1, 8 float4 each
        int k = threadIdx.x >> 1, cq = threadIdx.x & 1;
        const float* wrow = Wr + k * F_OUT;
        #pragma unroll
        for (int j = 0; j < 8; ++j) {
            int col = (cq + 2 * j) * 4;
            *(float4*)&wsd[k * 68 + col] = *(const float4*)(wrow + col);
        }
    }
    int row0 = blockIdx.x * 64;
    int ty = threadIdx.x >> 4, tx = threadIdx.x & 15;
    int lrow = threadIdx.x >> 2;
    int kq = threadIdx.x & 3;
    int grow = row0 + lrow; if (grow >= N) grow = N - 1;   // clamp, garbage ok
    const float* xrow = x + (size_t)grow * F_IN;
    float acc[4][4] = {};
    for (int kc = 0; kc < 2; ++kc) {
        __syncthreads();
        #pragma unroll
        for (int j = 0; j < 4; ++j) {
            int kk4 = kq + 4 * j;
            float4 v = *(const float4*)(xrow + kc * 64 + kk4 * 4);
            xs[(kk4 * 4 + 0) * 68 + lrow] = v.x;
            xs[(kk4 * 4 + 1) * 68 + lrow] = v.y;
            xs[(kk4 * 4 + 2) * 68 + lrow] = v.z;
            xs[(kk4 * 4 + 3) * 68 + lrow] = v.w;
        }
        __syncthreads();
        const float* wk = &wsd[kc * 64 * 68];
        #pragma unroll 8
        for (int kk = 0; kk < 64; ++kk) {
            float4 xa = *(const float4*)&xs[kk * 68 + ty * 4];
            float4 wb = *(const float4*)&wk[kk * 68 + tx * 4];
            acc[0][0] += xa.x * wb.x; acc[0][1] += xa.x * wb.y;
            acc[0][2] += xa.x * wb.z; acc[0][3] += xa.x * wb.w;
            acc[1][0] += xa.y * wb.x; acc[1][1] += xa.y * wb.y;
            acc[1][2] += xa.y * wb.z; acc[1][3] += xa.y * wb.w;
            acc[2][0] += xa.z * wb.x; acc[2][1] += xa.z * wb.y;
            acc[2][2] += xa.z * wb.z; acc[2][3] += xa.z * wb.w;
            acc[3][0] += xa.w * wb.x; acc[3][1] += xa.w * wb.y;
            acc[3][2] += xa.w * wb.z; acc[3][3] += xa.w * wb.w;
        }
    }
    const int* ipr = ip + (size_t)r * N;
    #pragma unroll
    for (int i = 0; i < 4; ++i) {
        int orow = row0 + ty * 4 + i;
        if (orow < N) {
            ushort4 v;
            v.x = f2bf(acc[i][0]); v.y = f2bf(acc[i][1]);
            v.z = f2bf(acc[i][2]); v.w = f2bf(acc[i][3]);
            size_t rb = (size_t)r * N;
            // pos half: own row (coalesced)
            *(ushort4*)(combined + (rb + orow) * 128 + tx * 4) = v;
            // neg half of row ip[orow]: wave writes 4 x 128B full segments
            int j = ipr[orow];
            *(ushort4*)(combined + (rb + j) * 128 + 64 + tx * 4) = v;
        }
    }
}

// ---------------- gather: one wave per (r, dst row); fused epilogue ---------
// Lane layout: lane owns combined channels [2*lane, 2*lane+1] (one uint load
// covers the full 256B row per wave). Lanes 0..31 -> pos ch 2l,2l+1;
// lanes 32..63 -> neg ch 2(l-32),2(l-32)+1.
// Edge loop: batch-8 predicated. j0/j1 readfirstlane'd -> csr entries come in
// via scalar loads; all 8 row loads issue before any FMA.
// Output stores are NON-TEMPORAL: out_pos/out_neg are write-once, never
// re-read on device. Without nt, the 153.6 MB output stream evicts the
// randomly-gathered `combined` (76.8 MB, should be L3-resident) -> 263 MB
// HBM FETCH observed vs ~94 MB unique. nt keeps combined in L3.
__global__ __launch_bounds__(256) void gather_kernel(const int2* __restrict__ csr,
                                                     const int* __restrict__ rowstart,
                                                     const float* __restrict__ dinv,
                                                     const unsigned short* __restrict__ combined,
                                                     const float* __restrict__ bs,
                                                     float* __restrict__ out_pos,
                                                     float* __restrict__ out_neg,
                                                     float* __restrict__ partial,
                                                     int N, int E) {
    int r = blockIdx.y;
    int lane = threadIdx.x & 63, wv = threadIdx.x >> 6;
    int i = blockIdx.x * 4 + wv;
    i = __builtin_amdgcn_readfirstlane(i);      // wave-uniform, make it scalar
    int c0 = (lane & 31) * 2;                   // output channel pair base
    __shared__ float ls[4][64];
    float p0 = 0.f, p1 = 0.f;                   // pos values for summary
    if (i < N) {
        const unsigned short* cw = combined + (size_t)r * N * 128;
        const int* rs = rowstart + (size_t)r * (N + 1);
        int j0 = rs[i], j1 = rs[i + 1];
        j0 = __builtin_amdgcn_readfirstlane(j0);
        j1 = __builtin_amdgcn_readfirstlane(j1);
        float di = dinv[(size_t)r * N + i];
        float w = di * di;
        // self term: whole 256B row in one coalesced wave access
        unsigned int sv = *(const unsigned int*)(cw + (size_t)i * 128 + 2 * lane);
        float acc0 = bf2f((unsigned short)sv) * w;
        float acc1 = bf2f((unsigned short)(sv >> 16)) * w;
        const int2* cs = csr + (size_t)r * E;
        int last = j1 - 1;
        for (int j = j0; j < j1; j += 8) {
            int2 e[8];
            float nm[8];
            #pragma unroll
            for (int k = 0; k < 8; ++k) {
                int idx = j + k;
                int ic = idx < last ? idx : last;        // clamp: always valid
                e[k] = cs[ic];                            // scalar load (uniform)
                nm[k] = (idx < j1) ? __int_as_float(e[k].y) : 0.f;
            }
            #pragma unroll
            for (int k = 0; k < 8; ++k) {
                unsigned int v = *(const unsigned int*)(cw + (size_t)e[k].x * 128 + 2 * lane);
                acc0 += bf2f((unsigned short)v) * nm[k];
                acc1 += bf2f((unsigned short)(v >> 16)) * nm[k];
            }
        }
        float2 bv = *(const float2*)(bs + r * F_OUT + c0);
        float q0 = acc0 + bv.x; q0 = q0 > 0.f ? q0 : 0.f;
        float q1 = acc1 + bv.y; q1 = q1 > 0.f ? q1 : 0.f;
        size_t off = (size_t)r * N * F_OUT + (size_t)i * F_OUT + c0;
        float* dst = (lane < 32) ? (out_pos + off) : (out_neg + off);
        f32x2 o; o.x = q0; o.y = q1;
        __builtin_nontemporal_store(o, (f32x2*)dst);    // nt: don't evict L3
        if (lane < 32) { p0 = q0; p1 = q1; }
    }
    if (lane < 32) { ls[wv][c0] = p0; ls[wv][c0 + 1] = p1; }
    __syncthreads();
    if (wv == 0) {
        float t = ls[0][lane] + ls[1][lane] + ls[2][lane] + ls[3][lane];
        atomicAdd(&partial[((size_t)r * 256 + (blockIdx.x & 255)) * F_OUT + lane], t);
    }
}

// ---------------- summary = mean over pos rows ------------------------------
__global__ __launch_bounds__(256) void summary_reduce(const float* __restrict__ partial,
                                                      float* __restrict__ summary,
                                                      float inv_n) {
    int r = blockIdx.x;
    int lane = threadIdx.x & 63, wv = threadIdx.x >> 6;
    __shared__ float ls[256];
    float s = 0.f;
    for (int c = wv; c < 256; c += 4)
        s += partial[((size_t)r * 256 + c) * F_OUT + lane];
    ls[threadIdx.x] = s;
    __syncthreads();
    if (wv == 0)
        summary[r * F_OUT + lane] =
            (ls[lane] + ls[64 + lane] + ls[128 + lane] + ls[192 + lane]) * inv_n;
}

extern "C" void kernel_launch(void* const* d_in, const int* in_sizes, int n_in,
                              void* d_out, int out_size, void* d_ws, size_t ws_size,
                              hipStream_t stream) {
    const float* x    = (const float*)d_in[0];
    const int*   ei   = (const int*)d_in[1];
    const int*   perm = (const int*)d_in[2];
    const float* Ws   = (const float*)d_in[3];
    const float* bs   = (const float*)d_in[4];

    const int N = in_sizes[0] / F_IN;          // 100000
    const int R = in_sizes[4] / F_OUT;         // 3
    const int E = in_sizes[1] / (2 * R);       // 600000

    float* out_pos = (float*)d_out;
    float* out_neg = out_pos + (size_t)R * N * F_OUT;
    float* summary = out_neg + (size_t)R * N * F_OUT;

    char* ws = (char*)d_ws;
    size_t off = 0;
    auto alloc = [&](size_t bytes) { void* p = ws + off;
        off += (bytes + 255) & ~(size_t)255; return p; };
    int*   deg      = (int*)  alloc((size_t)R * N * 4);   // -> cursor after scan
    float* dinv     = (float*)alloc((size_t)R * N * 4);
    int*   rowstart = (int*)  alloc((size_t)R * (N + 1) * 4);
    int*   ip       = (int*)  alloc((size_t)R * N * 4);
    int2*  csr      = (int2*) alloc((size_t)R * E * 8);
    unsigned short* combined = (unsigned short*)alloc((size_t)R * N * 128 * 2);
    float* partial  = (float*)alloc((size_t)R * 256 * F_OUT * 4);
    int*   psum     = (int*)  alloc((size_t)R * NCHUNK * 4);

    const int chunk = (N + NCHUNK - 1) / NCHUNK;

    hipMemsetAsync(deg, 0, (size_t)R * N * sizeof(int), stream);
    hipMemsetAsync(partial, 0, (size_t)R * 256 * F_OUT * sizeof(float), stream);

    deg_kernel<<<dim3((E + 255) / 256, R), 256, 0, stream>>>(ei, deg, N, E);
    invperm_kernel<<<dim3((N + 255) / 256, R), 256, 0, stream>>>(perm, ip, N);
    scan_partial<<<dim3(NCHUNK, R), 256, 0, stream>>>(deg, psum, N, chunk);
    scan_offsets<<<1, 256, 0, stream>>>(psum, rowstart, N, R);
    scan_apply<<<dim3(NCHUNK, R), 256, 0, stream>>>(deg, psum, rowstart, dinv, N, chunk);
    fill_csr<<<dim3((E + 255) / 256, R), 256, 0, stream>>>(ei, dinv, deg, csr, N, E);
    gemm_xw<<<dim3((N + 63) / 64, R), 256, 0, stream>>>(x, Ws, ip, combined, N);
    gather_kernel<<<dim3((N + 3) / 4, R), 256, 0, stream>>>(csr, rowstart, dinv,
                                                            combined, bs, out_pos,
                                                            out_neg, partial, N, E);
    summary_reduce<<<R, 256, 0, stream>>>(partial, summary, 1.0f / (float)N);
}